// Round 1
// 525.325 us; speedup vs baseline: 1.0548x; 1.0548x over previous
//
#include <hip/hip_runtime.h>
#include <hip/hip_bf16.h>

// Sizes from the reference
#define N_NODES 65536
#define CFCH 16
#define L0LEN 4097
#define L1LEN 16385
#define NSFC 2
#define LATD 128
#define HIDD 512
#define NROWS (CFCH * L0LEN * NSFC)   // 131104

typedef __attribute__((ext_vector_type(8))) short short8;
typedef __attribute__((ext_vector_type(4))) float f32x4;

__device__ __forceinline__ float fast_tanh(float x) {
    float ax = fabsf(x);
    float e = __expf(-2.0f * ax);
    float r = (1.0f - e) / (1.0f + e);
    return copysignf(r, x);
}

__device__ __forceinline__ ushort f2bf(float f) {   // fp32 -> bf16 RNE
    unsigned u = __float_as_uint(f);
    return (ushort)((u + 0x7fffu + ((u >> 16) & 1u)) >> 16);
}

__device__ __forceinline__ void split8(const float4 a, const float4 b, short8& hi, short8& lo) {
    float f[8] = {a.x, a.y, a.z, a.w, b.x, b.y, b.z, b.w};
#pragma unroll
    for (int e = 0; e < 8; ++e) {
        ushort h = f2bf(f[e]);
        hi[e] = (short)h;
        lo[e] = (short)f2bf(f[e] - __uint_as_float((unsigned)h << 16));
    }
}

// ---------------- fc1: h[b][j] = tanh(x[b,:]·W1[j,:] + b1[j]) -> bf16 hi/lo [b][k] ----------------
__global__ void fc1_kernel(const float* __restrict__ x, const float* __restrict__ W1,
                           const float* __restrict__ b1,
                           ushort* __restrict__ h1hi, ushort* __restrict__ h1lo) {
    int tid = blockIdx.x * 256 + threadIdx.x;   // 8192 threads
    int b = tid & 15;
    int j = tid >> 4;
    const float* xr = x + b * LATD;
    const float* wr = W1 + j * LATD;
    float acc = 0.f;
#pragma unroll 8
    for (int k = 0; k < LATD; ++k) acc = fmaf(xr[k], wr[k], acc);
    float h = fast_tanh(acc + b1[j]);
    ushort hi = f2bf(h);
    float hif = __uint_as_float((unsigned)hi << 16);
    ushort lo = f2bf(h - hif);
    h1hi[b * HIDD + j] = hi;
    h1lo[b * HIDD + j] = lo;
}

// ---------------- fc2 via MFMA: C[j,b] = tanh(W2[j,:]·h[:,b] + b2[j]) ----------------
// M=NROWS, N=16(batch), K=512. A=W2 (split bf16 hi/lo from registers, coalesced 128B-line
// global reads). B=h fragments from LDS. 3-term split: hi*hi + hi*lo + lo*hi.
__global__ void __launch_bounds__(256, 4) fc2_kernel(const float* __restrict__ W2,
                                                     const float* __restrict__ b2,
                                                     const ushort* __restrict__ h1hi,
                                                     const ushort* __restrict__ h1lo,
                                                     float* __restrict__ h2) {
    __shared__ __align__(16) ushort hB[2][16][520];   // [hi/lo][n=batch][k] bf16, pad row to 520
    for (int u = threadIdx.x; u < 2048; u += 256) {
        int arr = u >> 10, uu = u & 1023;
        int n = uu >> 6, kc = uu & 63;                 // 64 x 16B units per row
        const ushort* src = (arr ? h1lo : h1hi) + n * HIDD + kc * 8;
        *(uint4*)&hB[arr][n][kc * 8] = *(const uint4*)src;
    }
    __syncthreads();

    int tid = threadIdx.x;
    int w = tid >> 6, lane = tid & 63;
    int lm = lane & 15, lq = lane >> 4;
    int j0 = blockIdx.x * 128;                         // 128 rows per block, 2 M-tiles per wave
    int jr0 = j0 + (w * 2) * 16 + lm;     if (jr0 >= NROWS) jr0 = NROWS - 1;
    int jr1 = j0 + (w * 2 + 1) * 16 + lm; if (jr1 >= NROWS) jr1 = NROWS - 1;
    const float* a0p = W2 + (size_t)jr0 * HIDD + lq * 8;   // A-frag: m=lane&15, k=(lane>>4)*8+e
    const float* a1p = W2 + (size_t)jr1 * HIDD + lq * 8;
    const ushort* bhp = &hB[0][lm][lq * 8];                // B-frag: n=lane&15, k=(lane>>4)*8+e
    const ushort* blp = &hB[1][lm][lq * 8];
    f32x4 acc0 = {0.f, 0.f, 0.f, 0.f};
    f32x4 acc1 = {0.f, 0.f, 0.f, 0.f};

#pragma unroll 2
    for (int ks = 0; ks < 16; ++ks) {                  // K-steps of 32
        float4 a0a = *(const float4*)(a0p + ks * 32);
        float4 a0b = *(const float4*)(a0p + ks * 32 + 4);
        float4 a1a = *(const float4*)(a1p + ks * 32);
        float4 a1b = *(const float4*)(a1p + ks * 32 + 4);
        short8 bh = *(const short8*)(bhp + ks * 32);
        short8 bl = *(const short8*)(blp + ks * 32);
        short8 h0, l0, h1v, l1v;
        split8(a0a, a0b, h0, l0);
        split8(a1a, a1b, h1v, l1v);
        acc0 = __builtin_amdgcn_mfma_f32_16x16x32_bf16(h0, bh, acc0, 0, 0, 0);
        acc1 = __builtin_amdgcn_mfma_f32_16x16x32_bf16(h1v, bh, acc1, 0, 0, 0);
        acc0 = __builtin_amdgcn_mfma_f32_16x16x32_bf16(h0, bl, acc0, 0, 0, 0);
        acc1 = __builtin_amdgcn_mfma_f32_16x16x32_bf16(h1v, bl, acc1, 0, 0, 0);
        acc0 = __builtin_amdgcn_mfma_f32_16x16x32_bf16(l0, bh, acc0, 0, 0, 0);
        acc1 = __builtin_amdgcn_mfma_f32_16x16x32_bf16(l1v, bh, acc1, 0, 0, 0);
    }

    // D layout: n(col)=lane&15, m(row)=(lane>>4)*4+reg  [measured m89/m91]
#pragma unroll
    for (int mt = 0; mt < 2; ++mt) {
        f32x4 acc = mt ? acc1 : acc0;
        int jb = j0 + (w * 2 + mt) * 16 + lq * 4;
#pragma unroll
        for (int reg = 0; reg < 4; ++reg) {
            int j = jb + reg;
            if (j < NROWS) {
                float val = fast_tanh(acc[reg] + b2[j]);
                int ii = j & 1;
                int s = j >> 1;
                int c = s / L0LEN;
                int l = s - c * L0LEN;
                h2[((size_t)(ii * 16 + lm) * CFCH + c) * L0LEN + l] = val;
            }
        }
    }
}

// ---------------- fused conv0+conv1: t0 tile lives entirely in LDS ----------------
// Per block (bx, bb, i): 2048 final outputs O in [bx*2048, bx*2048+2048).
// conv0: t0[P] = tanh(b0[co] + sum_ci sum_t w0[ci][co][r+4t] * h2[ci][P/4+4-t]),  r=P&3
//        needed P-window: [p0, p0+519],  p0 = bx*512 - 4  (stored at p' = P-p0-1)
// conv1: out[O] = tanh(b1 + sum_ci sum_t w1[ci][r+4t] * t0[O/4+4-t])
// Accumulation order (ci-major, t-ascending, fmaf) identical to the unfused kernels.
#define H2ROW 144
#define T0ROW 520

__global__ void __launch_bounds__(256, 2) convfused_kernel(const float* __restrict__ h2,
        const float* __restrict__ ctw0, const float* __restrict__ ctb0,
        const float* __restrict__ ctw1, const float* __restrict__ ctb1,
        float* __restrict__ t1) {
    __shared__ float h2S[16 * H2ROW];      // 9.2 KB : h2 window, h2S[ci][xx] = h2[ci][q0+xx]
    __shared__ float w0T[16 * 16 * 32];    // 32 KB  : [(ci*16+co)*32 + r*8 + t] = ctw0[i][ci][co][r+4t]
    __shared__ float w1T[16 * 32];         // 2 KB   : [ci*32 + r*8 + t]        = ctw1[i][ci][0][r+4t]
    __shared__ float t0S[16 * T0ROW];      // 33.3 KB: [co*T0ROW + p'] , p' = p-1 (aligned conv1 reads)

    int bx = blockIdx.x, bb = blockIdx.y, i = blockIdx.z;
    int tid = threadIdx.x;
    int r = __builtin_amdgcn_readfirstlane(tid >> 6);  // wave-uniform output phase
    int lane = tid & 63;

    // ---- stage h2 window (140 cols x 16 ci), zero-padded outside [0, L0LEN) ----
    int q0 = (bx << 7) - 4;
    const float* hin = h2 + (size_t)((i * 16 + bb) * 16) * L0LEN;
#pragma unroll 1
    for (int u = tid; u < 16 * 140; u += 256) {
        int ci = u / 140;
        int xx = u - ci * 140;
        int q = q0 + xx;
        h2S[ci * H2ROW + xx] = (q >= 0 && q < L0LEN) ? hin[ci * L0LEN + q] : 0.f;
    }
    // ---- stage transposed conv0 weights (coalesced read, permuted LDS write) ----
    const float* w0g = ctw0 + (i << 13);
#pragma unroll 1
    for (int g = tid; g < 8192; g += 256) {
        int k = g & 31;
        w0T[(g & ~31) + ((k & 3) << 3) + (k >> 2)] = w0g[g];
    }
    // ---- stage transposed conv1 weights ----
    const float* w1g = ctw1 + (i << 9);
#pragma unroll 1
    for (int g = tid; g < 512; g += 256) {
        int k = g & 31;
        w1T[(g & ~31) + ((k & 3) << 3) + (k >> 2)] = w1g[g];
    }
    __syncthreads();

    int p0 = (bx << 9) - 4;

    // ---- conv0 stage: each lane computes quads Qb, Qb+1 (covers Q in [0,128)) for all 16 co ----
    {
        float acc[16][2];
#pragma unroll
        for (int co = 0; co < 16; ++co) { acc[co][0] = 0.f; acc[co][1] = 0.f; }
        int Qb = lane << 1;
#pragma unroll 1
        for (int ci = 0; ci < 16; ++ci) {
            const float* xb = &h2S[ci * H2ROW + Qb];
            float2 xA = *(const float2*)(xb);          // Qb even -> 8B aligned
            float2 xB = *(const float2*)(xb + 2);
            float2 xC = *(const float2*)(xb + 4);
            float2 xD = *(const float2*)(xb + 6);
            float x8v = xb[8];
            float x[9] = {xA.x, xA.y, xB.x, xB.y, xC.x, xC.y, xD.x, xD.y, x8v};
            const float* wbase = &w0T[(ci << 9) + (r << 3)];
#pragma unroll
            for (int co = 0; co < 16; ++co) {
                const float* wrow = wbase + (co << 5); // wave-uniform addr -> LDS broadcast
                float4 wa = *(const float4*)wrow;
                float4 wb4 = *(const float4*)(wrow + 4);
                // t ascending, x index = Q + 7 - t  (identical order to unfused conv0)
                acc[co][0] = fmaf(wa.x,  x[7], acc[co][0]);
                acc[co][0] = fmaf(wa.y,  x[6], acc[co][0]);
                acc[co][0] = fmaf(wa.z,  x[5], acc[co][0]);
                acc[co][0] = fmaf(wa.w,  x[4], acc[co][0]);
                acc[co][0] = fmaf(wb4.x, x[3], acc[co][0]);
                acc[co][0] = fmaf(wb4.y, x[2], acc[co][0]);
                acc[co][0] = fmaf(wb4.z, x[1], acc[co][0]);
                acc[co][0] = fmaf(wb4.w, x[0], acc[co][0]);
                acc[co][1] = fmaf(wa.x,  x[8], acc[co][1]);
                acc[co][1] = fmaf(wa.y,  x[7], acc[co][1]);
                acc[co][1] = fmaf(wa.z,  x[6], acc[co][1]);
                acc[co][1] = fmaf(wa.w,  x[5], acc[co][1]);
                acc[co][1] = fmaf(wb4.x, x[4], acc[co][1]);
                acc[co][1] = fmaf(wb4.y, x[3], acc[co][1]);
                acc[co][1] = fmaf(wb4.z, x[2], acc[co][1]);
                acc[co][1] = fmaf(wb4.w, x[1], acc[co][1]);
            }
        }
#pragma unroll
        for (int co = 0; co < 16; ++co) {
            float b0 = ctb0[(i << 4) + co];
#pragma unroll
            for (int j = 0; j < 2; ++j) {
                int p = ((Qb + j) << 2) + r;
                unsigned P = (unsigned)(p0 + p);
                float val = (P < L1LEN) ? fast_tanh(acc[co][j] + b0) : 0.f;  // zero pad like unfused
                if (p >= 1) t0S[co * T0ROW + (p - 1)] = val;
            }
        }
    }

    // ---- conv0 tail: quads 128,129 (one value per thread, 128 threads) ----
    if (tid < 128) {
        int co = tid >> 3;
        int Qt = 128 + ((tid >> 2) & 1);
        int rt = tid & 3;
        float acct = 0.f;
#pragma unroll 1
        for (int ci = 0; ci < 16; ++ci) {
            const float* xb = &h2S[ci * H2ROW + Qt];
            const float* wrow = &w0T[(ci << 9) + (co << 5) + (rt << 3)];
#pragma unroll
            for (int t = 0; t < 8; ++t)
                acct = fmaf(wrow[t], xb[7 - t], acct);
        }
        float b0 = ctb0[(i << 4) + co];
        int p = (Qt << 2) + rt;                 // p in [512,519] -> p' in [511,518]
        unsigned P = (unsigned)(p0 + p);
        t0S[co * T0ROW + (p - 1)] = (P < L1LEN) ? fast_tanh(acct + b0) : 0.f;
    }
    __syncthreads();

    // ---- conv1 stage: each lane computes 8 quads (Qb1..Qb1+7), aligned b128 LDS reads ----
    {
        int Qb1 = lane << 3;
        float acc1[8];
#pragma unroll
        for (int j = 0; j < 8; ++j) acc1[j] = 0.f;
#pragma unroll 1
        for (int ci = 0; ci < 16; ++ci) {
            const float* xb = &t0S[ci * T0ROW + Qb1];  // 32B-aligned, lane-stride 16B
            float4 xa = *(const float4*)(xb);
            float4 xv = *(const float4*)(xb + 4);
            float4 xc = *(const float4*)(xb + 8);
            float4 xd = *(const float4*)(xb + 12);
            float x[16] = {xa.x, xa.y, xa.z, xa.w, xv.x, xv.y, xv.z, xv.w,
                           xc.x, xc.y, xc.z, xc.w, xd.x, xd.y, xd.z, xd.w};
            const float* wrow = &w1T[(ci << 5) + (r << 3)];
            float4 wa = *(const float4*)wrow;
            float4 wb4 = *(const float4*)(wrow + 4);
            float wt[8] = {wa.x, wa.y, wa.z, wa.w, wb4.x, wb4.y, wb4.z, wb4.w};
#pragma unroll
            for (int j = 0; j < 8; ++j) {
#pragma unroll
                for (int t = 0; t < 8; ++t)
                    acc1[j] = fmaf(wt[t], x[j + 7 - t], acc1[j]);
            }
        }
        float bias = ctb1[i];
        float* dst = t1 + (size_t)(i * 16 + bb) * (size_t)N_NODES;
        int o0 = bx << 11;
#pragma unroll
        for (int j = 0; j < 8; ++j) {
            int o = o0 + ((Qb1 + j) << 2) + r;
            dst[o] = fast_tanh(acc1[j] + bias);
        }
    }
}

// ---------------- gather + per-sfc NN + final NN + output linear ----------------
__global__ void __launch_bounds__(256) final_kernel(const float* __restrict__ t1,
        const float* __restrict__ sps_w, const float* __restrict__ sps_b,
        const float* __restrict__ final_w, const float* __restrict__ final_b,
        const float* __restrict__ out_w, const float* __restrict__ out_b,
        const int* __restrict__ ord_idx, float* __restrict__ out) {
    int g = blockIdx.x * 256 + threadIdx.x;   // 262144 threads
    int b = g >> 14;
    int n0 = (g & 16383) << 2;                // 4 nodes per thread
    float z[2][4];
#pragma unroll
    for (int i = 0; i < 2; ++i) {
        const int* od = ord_idx + i * N_NODES;
        int4 mid = *(const int4*)(od + n0);
        int idx0 = (n0 == 0) ? mid.x : od[n0 - 1];
        int idx5 = (n0 + 4 >= N_NODES) ? mid.w : od[n0 + 4];
        const float* tb = t1 + ((size_t)(i * 16 + b) << 16);
        float v0 = tb[idx0], v1 = tb[mid.x], v2 = tb[mid.y],
              v3 = tb[mid.z], v4 = tb[mid.w], v5 = tb[idx5];
        const float* sw = sps_w + ((size_t)i * N_NODES + n0) * 3;
        float4 swa = *(const float4*)sw;
        float4 swb = *(const float4*)(sw + 4);
        float4 swc = *(const float4*)(sw + 8);
        float4 sb = *(const float4*)(sps_b + (size_t)i * N_NODES + n0);
        z[i][0] = fast_tanh(fmaf(v0, swa.x, fmaf(v1, swa.y, fmaf(v2, swa.z, sb.x))));
        z[i][1] = fast_tanh(fmaf(v1, swa.w, fmaf(v2, swb.x, fmaf(v3, swb.y, sb.y))));
        z[i][2] = fast_tanh(fmaf(v2, swb.z, fmaf(v3, swb.w, fmaf(v4, swc.x, sb.z))));
        z[i][3] = fast_tanh(fmaf(v3, swc.y, fmaf(v4, swc.z, fmaf(v5, swc.w, sb.w))));
    }
    float4 fwa = *(const float4*)(final_w + (size_t)n0 * 2);
    float4 fwb = *(const float4*)(final_w + (size_t)n0 * 2 + 4);
    float4 fb = *(const float4*)(final_b + n0);
    float4 ow = *(const float4*)(out_w + n0);
    float4 ob = *(const float4*)(out_b + n0);
    float4 r;
    r.x = fmaf(fast_tanh(fmaf(z[0][0], fwa.x, fmaf(z[1][0], fwa.y, fb.x))), ow.x, ob.x);
    r.y = fmaf(fast_tanh(fmaf(z[0][1], fwa.z, fmaf(z[1][1], fwa.w, fb.y))), ow.y, ob.y);
    r.z = fmaf(fast_tanh(fmaf(z[0][2], fwb.x, fmaf(z[1][2], fwb.y, fb.z))), ow.z, ob.z);
    r.w = fmaf(fast_tanh(fmaf(z[0][3], fwb.z, fmaf(z[1][3], fwb.w, fb.w))), ow.w, ob.w);
    *(float4*)(out + ((size_t)b << 16) + n0) = r;
}

extern "C" void kernel_launch(void* const* d_in, const int* in_sizes, int n_in,
                              void* d_out, int out_size, void* d_ws, size_t ws_size,
                              hipStream_t stream) {
    const float* x       = (const float*)d_in[0];
    const float* W1      = (const float*)d_in[1];
    const float* b1      = (const float*)d_in[2];
    const float* W2      = (const float*)d_in[3];
    const float* b2      = (const float*)d_in[4];
    const float* ctw0    = (const float*)d_in[5];
    const float* ctb0    = (const float*)d_in[6];
    const float* ctw1    = (const float*)d_in[7];
    const float* ctb1    = (const float*)d_in[8];
    const float* sps_w   = (const float*)d_in[9];
    const float* sps_b   = (const float*)d_in[10];
    const float* final_w = (const float*)d_in[11];
    const float* final_b = (const float*)d_in[12];
    const float* out_w   = (const float*)d_in[13];
    const float* out_b   = (const float*)d_in[14];
    const int* ord_idx   = (const int*)d_in[15];

    float* ws  = (float*)d_ws;
    float* h2  = ws;                         // 2097664 f  [2][16][16][4097]
    float* t1  = h2 + 2097664;               // 2097152 f  [2][16][65536]
    ushort* h1hi = (ushort*)(t1 + 2097152);  // 8192 ushorts
    ushort* h1lo = h1hi + 8192;
    float* out = (float*)d_out;

    hipLaunchKernelGGL(fc1_kernel, dim3(32), dim3(256), 0, stream, x, W1, b1, h1hi, h1lo);
    hipLaunchKernelGGL(fc2_kernel, dim3((NROWS + 127) / 128), dim3(256), 0, stream,
                       W2, b2, h1hi, h1lo, h2);
    hipLaunchKernelGGL(convfused_kernel, dim3(32, 16, 2), dim3(256), 0, stream,
                       h2, ctw0, ctb0, ctw1, ctb1, t1);
    hipLaunchKernelGGL(final_kernel, dim3(1024), dim3(256), 0, stream,
                       t1, sps_w, sps_b, final_w, final_b, out_w, out_b,
                       ord_idx, out);
}

// Round 2
// 509.517 us; speedup vs baseline: 1.0875x; 1.0310x over previous
//
#include <hip/hip_runtime.h>
#include <hip/hip_bf16.h>

// Sizes from the reference
#define N_NODES 65536
#define CFCH 16
#define L0LEN 4097
#define L1LEN 16385
#define NSFC 2
#define LATD 128
#define HIDD 512
#define NROWS (CFCH * L0LEN * NSFC)   // 131104

typedef __attribute__((ext_vector_type(8))) short short8;
typedef __attribute__((ext_vector_type(4))) float f32x4;

__device__ __forceinline__ float fast_tanh(float x) {
    float ax = fabsf(x);
    float e = __expf(-2.0f * ax);
    float r = (1.0f - e) / (1.0f + e);
    return copysignf(r, x);
}

__device__ __forceinline__ ushort f2bf(float f) {   // fp32 -> bf16 RNE
    unsigned u = __float_as_uint(f);
    return (ushort)((u + 0x7fffu + ((u >> 16) & 1u)) >> 16);
}

__device__ __forceinline__ void split8(const float4 a, const float4 b, short8& hi, short8& lo) {
    float f[8] = {a.x, a.y, a.z, a.w, b.x, b.y, b.z, b.w};
#pragma unroll
    for (int e = 0; e < 8; ++e) {
        ushort h = f2bf(f[e]);
        hi[e] = (short)h;
        lo[e] = (short)f2bf(f[e] - __uint_as_float((unsigned)h << 16));
    }
}

// ---------------- fc1 (blocks 0..31) + weight-transpose prep (blocks 32..99) ----------------
// wprep: w0G[((i*4+r)*16+ci)*128 + co*8 + t] = ctw0[i][ci][co][r+4t]
//        w1G[((i*4+r)*16+ci)*8  + t]        = ctw1[i][ci][0][r+4t]
__global__ void fc1_kernel(const float* __restrict__ x, const float* __restrict__ W1,
                           const float* __restrict__ b1,
                           const float* __restrict__ ctw0, const float* __restrict__ ctw1,
                           ushort* __restrict__ h1hi, ushort* __restrict__ h1lo,
                           float* __restrict__ w0G, float* __restrict__ w1G) {
    if (blockIdx.x >= 32) {
        int g = (blockIdx.x - 32) * 256 + threadIdx.x;
        if (g < 16384) {
            int t = g & 7, co = (g >> 3) & 15, ci = (g >> 7) & 15, r = (g >> 11) & 3, i = g >> 13;
            w0G[g] = ctw0[(((i * 16 + ci) * 16 + co) << 5) + r + (t << 2)];
        } else if (g < 17408) {
            int gg = g - 16384;
            int t = gg & 7, ci = (gg >> 3) & 15, r = (gg >> 7) & 3, i = gg >> 9;
            w1G[gg] = ctw1[((i * 16 + ci) << 5) + r + (t << 2)];
        }
        return;
    }
    int tid = blockIdx.x * 256 + threadIdx.x;   // 8192 threads
    int b = tid & 15;
    int j = tid >> 4;
    const float* xr = x + b * LATD;
    const float* wr = W1 + j * LATD;
    float acc = 0.f;
#pragma unroll 8
    for (int k = 0; k < LATD; ++k) acc = fmaf(xr[k], wr[k], acc);
    float h = fast_tanh(acc + b1[j]);
    ushort hi = f2bf(h);
    float hif = __uint_as_float((unsigned)hi << 16);
    ushort lo = f2bf(h - hif);
    h1hi[b * HIDD + j] = hi;
    h1lo[b * HIDD + j] = lo;
}

// ---------------- fc2 via MFMA: C[j,b] = tanh(W2[j,:]·h[:,b] + b2[j]) ----------------
// M=NROWS, N=16(batch), K=512. A=W2 (split bf16 hi/lo from registers, coalesced 128B-line
// global reads). B=h fragments from LDS. 3-term split: hi*hi + hi*lo + lo*hi.
__global__ void __launch_bounds__(256, 4) fc2_kernel(const float* __restrict__ W2,
                                                     const float* __restrict__ b2,
                                                     const ushort* __restrict__ h1hi,
                                                     const ushort* __restrict__ h1lo,
                                                     float* __restrict__ h2) {
    __shared__ __align__(16) ushort hB[2][16][520];   // [hi/lo][n=batch][k] bf16, pad row to 520
    for (int u = threadIdx.x; u < 2048; u += 256) {
        int arr = u >> 10, uu = u & 1023;
        int n = uu >> 6, kc = uu & 63;                 // 64 x 16B units per row
        const ushort* src = (arr ? h1lo : h1hi) + n * HIDD + kc * 8;
        *(uint4*)&hB[arr][n][kc * 8] = *(const uint4*)src;
    }
    __syncthreads();

    int tid = threadIdx.x;
    int w = tid >> 6, lane = tid & 63;
    int lm = lane & 15, lq = lane >> 4;
    int j0 = blockIdx.x * 128;                         // 128 rows per block, 2 M-tiles per wave
    int jr0 = j0 + (w * 2) * 16 + lm;     if (jr0 >= NROWS) jr0 = NROWS - 1;
    int jr1 = j0 + (w * 2 + 1) * 16 + lm; if (jr1 >= NROWS) jr1 = NROWS - 1;
    const float* a0p = W2 + (size_t)jr0 * HIDD + lq * 8;   // A-frag: m=lane&15, k=(lane>>4)*8+e
    const float* a1p = W2 + (size_t)jr1 * HIDD + lq * 8;
    const ushort* bhp = &hB[0][lm][lq * 8];                // B-frag: n=lane&15, k=(lane>>4)*8+e
    const ushort* blp = &hB[1][lm][lq * 8];
    f32x4 acc0 = {0.f, 0.f, 0.f, 0.f};
    f32x4 acc1 = {0.f, 0.f, 0.f, 0.f};

#pragma unroll 2
    for (int ks = 0; ks < 16; ++ks) {                  // K-steps of 32
        float4 a0a = *(const float4*)(a0p + ks * 32);
        float4 a0b = *(const float4*)(a0p + ks * 32 + 4);
        float4 a1a = *(const float4*)(a1p + ks * 32);
        float4 a1b = *(const float4*)(a1p + ks * 32 + 4);
        short8 bh = *(const short8*)(bhp + ks * 32);
        short8 bl = *(const short8*)(blp + ks * 32);
        short8 h0, l0, h1v, l1v;
        split8(a0a, a0b, h0, l0);
        split8(a1a, a1b, h1v, l1v);
        acc0 = __builtin_amdgcn_mfma_f32_16x16x32_bf16(h0, bh, acc0, 0, 0, 0);
        acc1 = __builtin_amdgcn_mfma_f32_16x16x32_bf16(h1v, bh, acc1, 0, 0, 0);
        acc0 = __builtin_amdgcn_mfma_f32_16x16x32_bf16(h0, bl, acc0, 0, 0, 0);
        acc1 = __builtin_amdgcn_mfma_f32_16x16x32_bf16(h1v, bl, acc1, 0, 0, 0);
        acc0 = __builtin_amdgcn_mfma_f32_16x16x32_bf16(l0, bh, acc0, 0, 0, 0);
        acc1 = __builtin_amdgcn_mfma_f32_16x16x32_bf16(l1v, bh, acc1, 0, 0, 0);
    }

    // D layout: n(col)=lane&15, m(row)=(lane>>4)*4+reg  [measured m89/m91]
#pragma unroll
    for (int mt = 0; mt < 2; ++mt) {
        f32x4 acc = mt ? acc1 : acc0;
        int jb = j0 + (w * 2 + mt) * 16 + lq * 4;
#pragma unroll
        for (int reg = 0; reg < 4; ++reg) {
            int j = jb + reg;
            if (j < NROWS) {
                float val = fast_tanh(acc[reg] + b2[j]);
                int ii = j & 1;
                int s = j >> 1;
                int c = s / L0LEN;
                int l = s - c * L0LEN;
                h2[((size_t)(ii * 16 + lm) * CFCH + c) * L0LEN + l] = val;
            }
        }
    }
}

// ---------------- fused conv0+conv1: t0 tile in LDS, weights via scalar loads ----------------
// Per block (bx, bb, i): 2048 final outputs O in [bx*2048, bx*2048+2048).
// conv0: t0[P] = tanh(b0[co] + sum_ci sum_t w0[ci][co][r+4t] * h2[ci][P/4+4-t]),  r=P&3
//        needed P-window: [p0, p0+519],  p0 = bx*512 - 4  (stored at p' = P-p0-1)
// conv1: out[O] = tanh(b1 + sum_ci sum_t w1[ci][r+4t] * t0[O/4+4-t])
// Weights read from w0G/w1G with fully wave-uniform addresses -> s_load (constant cache),
// zero LDS traffic. Accumulation order identical to the unfused kernels.
#define H2ROW 144
#define T0ROW 520

__global__ void __launch_bounds__(256, 3) convfused_kernel(const float* __restrict__ h2,
        const float* __restrict__ w0G, const float* __restrict__ ctb0,
        const float* __restrict__ w1G, const float* __restrict__ ctb1,
        float* __restrict__ t1) {
    __shared__ float h2S[16 * H2ROW];      // 9.2 KB : h2 window, h2S[ci][xx] = h2[ci][q0+xx]
    __shared__ float t0S[16 * T0ROW];      // 33.3 KB: [co*T0ROW + p'] , p' = p-1 (aligned conv1 reads)

    int bx = blockIdx.x, bb = blockIdx.y, i = blockIdx.z;
    int tid = threadIdx.x;
    int r = __builtin_amdgcn_readfirstlane(tid >> 6);  // wave-uniform output phase
    int lane = tid & 63;

    // ---- stage h2 window (140 cols x 16 ci), zero-padded outside [0, L0LEN) ----
    int q0 = (bx << 7) - 4;
    const float* hin = h2 + (size_t)((i * 16 + bb) * 16) * L0LEN;
#pragma unroll 1
    for (int u = tid; u < 16 * 140; u += 256) {
        int ci = u / 140;
        int xx = u - ci * 140;
        int q = q0 + xx;
        h2S[ci * H2ROW + xx] = (q >= 0 && q < L0LEN) ? hin[ci * L0LEN + q] : 0.f;
    }
    __syncthreads();

    int p0 = (bx << 9) - 4;
    const float* w0r = w0G + (((i << 2) + r) << 11);   // [ci][co][t] for this (i, r)

    // ---- conv0 stage: each lane computes quads Qb, Qb+1 (covers Q in [0,128)) for all 16 co ----
    {
        float acc[16][2];
#pragma unroll
        for (int co = 0; co < 16; ++co) { acc[co][0] = 0.f; acc[co][1] = 0.f; }
        int Qb = lane << 1;
#pragma unroll 1
        for (int ci = 0; ci < 16; ++ci) {
            const float* xb = &h2S[ci * H2ROW + Qb];
            float2 xA = *(const float2*)(xb);          // Qb even -> 8B aligned
            float2 xB = *(const float2*)(xb + 2);
            float2 xC = *(const float2*)(xb + 4);
            float2 xD = *(const float2*)(xb + 6);
            float x8v = xb[8];
            float x[9] = {xA.x, xA.y, xB.x, xB.y, xC.x, xC.y, xD.x, xD.y, x8v};
            const float* wci = w0r + (ci << 7);        // wave-uniform -> s_load
#pragma unroll
            for (int co = 0; co < 16; ++co) {
                const float* wrow = wci + (co << 3);
                float4 wa = *(const float4*)wrow;
                float4 wb4 = *(const float4*)(wrow + 4);
                // t ascending, x index = Q + 7 - t  (identical order to unfused conv0)
                acc[co][0] = fmaf(wa.x,  x[7], acc[co][0]);
                acc[co][0] = fmaf(wa.y,  x[6], acc[co][0]);
                acc[co][0] = fmaf(wa.z,  x[5], acc[co][0]);
                acc[co][0] = fmaf(wa.w,  x[4], acc[co][0]);
                acc[co][0] = fmaf(wb4.x, x[3], acc[co][0]);
                acc[co][0] = fmaf(wb4.y, x[2], acc[co][0]);
                acc[co][0] = fmaf(wb4.z, x[1], acc[co][0]);
                acc[co][0] = fmaf(wb4.w, x[0], acc[co][0]);
                acc[co][1] = fmaf(wa.x,  x[8], acc[co][1]);
                acc[co][1] = fmaf(wa.y,  x[7], acc[co][1]);
                acc[co][1] = fmaf(wa.z,  x[6], acc[co][1]);
                acc[co][1] = fmaf(wa.w,  x[5], acc[co][1]);
                acc[co][1] = fmaf(wb4.x, x[4], acc[co][1]);
                acc[co][1] = fmaf(wb4.y, x[3], acc[co][1]);
                acc[co][1] = fmaf(wb4.z, x[2], acc[co][1]);
                acc[co][1] = fmaf(wb4.w, x[1], acc[co][1]);
            }
        }
#pragma unroll
        for (int co = 0; co < 16; ++co) {
            float b0 = ctb0[(i << 4) + co];
#pragma unroll
            for (int j = 0; j < 2; ++j) {
                int p = ((Qb + j) << 2) + r;
                unsigned P = (unsigned)(p0 + p);
                float val = (P < L1LEN) ? fast_tanh(acc[co][j] + b0) : 0.f;  // zero pad like unfused
                if (p >= 1) t0S[co * T0ROW + (p - 1)] = val;
            }
        }
    }

    // ---- conv0 tail: quads 128,129 (one value per thread, 128 threads) ----
    if (tid < 128) {
        int co = tid >> 3;
        int Qt = 128 + ((tid >> 2) & 1);
        int rt = tid & 3;
        float acct = 0.f;
        const float* wt0 = w0G + (((i << 2) + rt) << 11) + (co << 3);
#pragma unroll 1
        for (int ci = 0; ci < 16; ++ci) {
            const float* xb = &h2S[ci * H2ROW + Qt];
            const float* wrow = wt0 + (ci << 7);       // per-lane addr -> vector load (tiny, L2-hot)
#pragma unroll
            for (int t = 0; t < 8; ++t)
                acct = fmaf(wrow[t], xb[7 - t], acct);
        }
        float b0 = ctb0[(i << 4) + co];
        int p = (Qt << 2) + rt;                 // p in [512,519] -> p' in [511,518]
        unsigned P = (unsigned)(p0 + p);
        t0S[co * T0ROW + (p - 1)] = (P < L1LEN) ? fast_tanh(acct + b0) : 0.f;
    }
    __syncthreads();

    // ---- conv1 stage: each lane computes 8 quads (Qb1..Qb1+7), aligned b128 LDS reads ----
    {
        int Qb1 = lane << 3;
        float acc1[8];
#pragma unroll
        for (int j = 0; j < 8; ++j) acc1[j] = 0.f;
        const float* w1r = w1G + (((i << 2) + r) << 7);
#pragma unroll 1
        for (int ci = 0; ci < 16; ++ci) {
            const float* xb = &t0S[ci * T0ROW + Qb1];  // 32B-aligned, lane-stride 16B
            float4 xa = *(const float4*)(xb);
            float4 xv = *(const float4*)(xb + 4);
            float4 xc = *(const float4*)(xb + 8);
            float4 xd = *(const float4*)(xb + 12);
            float x[16] = {xa.x, xa.y, xa.z, xa.w, xv.x, xv.y, xv.z, xv.w,
                           xc.x, xc.y, xc.z, xc.w, xd.x, xd.y, xd.z, xd.w};
            const float* wrow = w1r + (ci << 3);       // wave-uniform -> s_load
            float4 wa = *(const float4*)wrow;
            float4 wb4 = *(const float4*)(wrow + 4);
            float wt[8] = {wa.x, wa.y, wa.z, wa.w, wb4.x, wb4.y, wb4.z, wb4.w};
#pragma unroll
            for (int j = 0; j < 8; ++j) {
#pragma unroll
                for (int t = 0; t < 8; ++t)
                    acc1[j] = fmaf(wt[t], x[j + 7 - t], acc1[j]);
            }
        }
        float bias = ctb1[i];
        float* dst = t1 + (size_t)(i * 16 + bb) * (size_t)N_NODES;
        int o0 = bx << 11;
#pragma unroll
        for (int j = 0; j < 8; ++j) {
            int o = o0 + ((Qb1 + j) << 2) + r;
            dst[o] = fast_tanh(acc1[j] + bias);
        }
    }
}

// ---------------- gather + per-sfc NN + final NN + output linear ----------------
__global__ void __launch_bounds__(256) final_kernel(const float* __restrict__ t1,
        const float* __restrict__ sps_w, const float* __restrict__ sps_b,
        const float* __restrict__ final_w, const float* __restrict__ final_b,
        const float* __restrict__ out_w, const float* __restrict__ out_b,
        const int* __restrict__ ord_idx, float* __restrict__ out) {
    int g = blockIdx.x * 256 + threadIdx.x;   // 262144 threads
    int b = g >> 14;
    int n0 = (g & 16383) << 2;                // 4 nodes per thread
    float z[2][4];
#pragma unroll
    for (int i = 0; i < 2; ++i) {
        const int* od = ord_idx + i * N_NODES;
        int4 mid = *(const int4*)(od + n0);
        int idx0 = (n0 == 0) ? mid.x : od[n0 - 1];
        int idx5 = (n0 + 4 >= N_NODES) ? mid.w : od[n0 + 4];
        const float* tb = t1 + ((size_t)(i * 16 + b) << 16);
        float v0 = tb[idx0], v1 = tb[mid.x], v2 = tb[mid.y],
              v3 = tb[mid.z], v4 = tb[mid.w], v5 = tb[idx5];
        const float* sw = sps_w + ((size_t)i * N_NODES + n0) * 3;
        float4 swa = *(const float4*)sw;
        float4 swb = *(const float4*)(sw + 4);
        float4 swc = *(const float4*)(sw + 8);
        float4 sb = *(const float4*)(sps_b + (size_t)i * N_NODES + n0);
        z[i][0] = fast_tanh(fmaf(v0, swa.x, fmaf(v1, swa.y, fmaf(v2, swa.z, sb.x))));
        z[i][1] = fast_tanh(fmaf(v1, swa.w, fmaf(v2, swb.x, fmaf(v3, swb.y, sb.y))));
        z[i][2] = fast_tanh(fmaf(v2, swb.z, fmaf(v3, swb.w, fmaf(v4, swc.x, sb.z))));
        z[i][3] = fast_tanh(fmaf(v3, swc.y, fmaf(v4, swc.z, fmaf(v5, swc.w, sb.w))));
    }
    float4 fwa = *(const float4*)(final_w + (size_t)n0 * 2);
    float4 fwb = *(const float4*)(final_w + (size_t)n0 * 2 + 4);
    float4 fb = *(const float4*)(final_b + n0);
    float4 ow = *(const float4*)(out_w + n0);
    float4 ob = *(const float4*)(out_b + n0);
    float4 r;
    r.x = fmaf(fast_tanh(fmaf(z[0][0], fwa.x, fmaf(z[1][0], fwa.y, fb.x))), ow.x, ob.x);
    r.y = fmaf(fast_tanh(fmaf(z[0][1], fwa.z, fmaf(z[1][1], fwa.w, fb.y))), ow.y, ob.y);
    r.z = fmaf(fast_tanh(fmaf(z[0][2], fwb.x, fmaf(z[1][2], fwb.y, fb.z))), ow.z, ob.z);
    r.w = fmaf(fast_tanh(fmaf(z[0][3], fwb.z, fmaf(z[1][3], fwb.w, fb.w))), ow.w, ob.w);
    *(float4*)(out + ((size_t)b << 16) + n0) = r;
}

extern "C" void kernel_launch(void* const* d_in, const int* in_sizes, int n_in,
                              void* d_out, int out_size, void* d_ws, size_t ws_size,
                              hipStream_t stream) {
    const float* x       = (const float*)d_in[0];
    const float* W1      = (const float*)d_in[1];
    const float* b1      = (const float*)d_in[2];
    const float* W2      = (const float*)d_in[3];
    const float* b2      = (const float*)d_in[4];
    const float* ctw0    = (const float*)d_in[5];
    const float* ctb0    = (const float*)d_in[6];
    const float* ctw1    = (const float*)d_in[7];
    const float* ctb1    = (const float*)d_in[8];
    const float* sps_w   = (const float*)d_in[9];
    const float* sps_b   = (const float*)d_in[10];
    const float* final_w = (const float*)d_in[11];
    const float* final_b = (const float*)d_in[12];
    const float* out_w   = (const float*)d_in[13];
    const float* out_b   = (const float*)d_in[14];
    const int* ord_idx   = (const int*)d_in[15];

    float* ws  = (float*)d_ws;
    float* h2  = ws;                         // 2097664 f  [2][16][16][4097]
    float* t1  = h2 + 2097664;               // 2097152 f  [2][16][65536]
    ushort* h1hi = (ushort*)(t1 + 2097152);  // 8192 ushorts
    ushort* h1lo = h1hi + 8192;
    float* w0G = (float*)(h1lo + 8192);      // 16384 f  [2][4][16][16][8]
    float* w1G = w0G + 16384;                // 1024 f   [2][4][16][8]
    float* out = (float*)d_out;

    hipLaunchKernelGGL(fc1_kernel, dim3(100), dim3(256), 0, stream,
                       x, W1, b1, ctw0, ctw1, h1hi, h1lo, w0G, w1G);
    hipLaunchKernelGGL(fc2_kernel, dim3((NROWS + 127) / 128), dim3(256), 0, stream,
                       W2, b2, h1hi, h1lo, h2);
    hipLaunchKernelGGL(convfused_kernel, dim3(32, 16, 2), dim3(256), 0, stream,
                       h2, w0G, ctb0, w1G, ctb1, t1);
    hipLaunchKernelGGL(final_kernel, dim3(1024), dim3(256), 0, stream,
                       t1, sps_w, sps_b, final_w, final_b, out_w, out_b,
                       ord_idx, out);
}

// Round 3
// 508.293 us; speedup vs baseline: 1.0901x; 1.0024x over previous
//
#include <hip/hip_runtime.h>
#include <hip/hip_bf16.h>

// Sizes from the reference
#define N_NODES 65536
#define CFCH 16
#define L0LEN 4097
#define L1LEN 16385
#define NSFC 2
#define LATD 128
#define HIDD 512
#define NROWS (CFCH * L0LEN * NSFC)   // 131104

typedef __attribute__((ext_vector_type(8))) short short8;
typedef __attribute__((ext_vector_type(4))) float f32x4;

__device__ __forceinline__ float fast_tanh(float x) {
    float ax = fabsf(x);
    float e = __expf(-2.0f * ax);
    float r = (1.0f - e) / (1.0f + e);
    return copysignf(r, x);
}

__device__ __forceinline__ ushort f2bf(float f) {   // fp32 -> bf16 RNE
    unsigned u = __float_as_uint(f);
    return (ushort)((u + 0x7fffu + ((u >> 16) & 1u)) >> 16);
}

__device__ __forceinline__ void split8(const float4 a, const float4 b, short8& hi, short8& lo) {
    float f[8] = {a.x, a.y, a.z, a.w, b.x, b.y, b.z, b.w};
#pragma unroll
    for (int e = 0; e < 8; ++e) {
        ushort h = f2bf(f[e]);
        hi[e] = (short)h;
        lo[e] = (short)f2bf(f[e] - __uint_as_float((unsigned)h << 16));
    }
}

// ---------------- fc1 (blocks 0..31) + weight-transpose prep (blocks 32..99) ----------------
// wprep: w0G[((i*4+r)*16+ci)*128 + co*8 + t] = ctw0[i][ci][co][r+4t]
//        w1G[((i*4+r)*16+ci)*8  + t]        = ctw1[i][ci][0][r+4t]
__global__ void fc1_kernel(const float* __restrict__ x, const float* __restrict__ W1,
                           const float* __restrict__ b1,
                           const float* __restrict__ ctw0, const float* __restrict__ ctw1,
                           ushort* __restrict__ h1hi, ushort* __restrict__ h1lo,
                           float* __restrict__ w0G, float* __restrict__ w1G) {
    if (blockIdx.x >= 32) {
        int g = (blockIdx.x - 32) * 256 + threadIdx.x;
        if (g < 16384) {
            int t = g & 7, co = (g >> 3) & 15, ci = (g >> 7) & 15, r = (g >> 11) & 3, i = g >> 13;
            w0G[g] = ctw0[(((i * 16 + ci) * 16 + co) << 5) + r + (t << 2)];
        } else if (g < 17408) {
            int gg = g - 16384;
            int t = gg & 7, ci = (gg >> 3) & 15, r = (gg >> 7) & 3, i = gg >> 9;
            w1G[gg] = ctw1[((i * 16 + ci) << 5) + r + (t << 2)];
        }
        return;
    }
    int tid = blockIdx.x * 256 + threadIdx.x;   // 8192 threads
    int b = tid & 15;
    int j = tid >> 4;
    const float* xr = x + b * LATD;
    const float* wr = W1 + j * LATD;
    float acc = 0.f;
#pragma unroll 8
    for (int k = 0; k < LATD; ++k) acc = fmaf(xr[k], wr[k], acc);
    float h = fast_tanh(acc + b1[j]);
    ushort hi = f2bf(h);
    float hif = __uint_as_float((unsigned)hi << 16);
    ushort lo = f2bf(h - hif);
    h1hi[b * HIDD + j] = hi;
    h1lo[b * HIDD + j] = lo;
}

// ---------------- fc2 via MFMA: C[j,b] = tanh(W2[j,:]·h[:,b] + b2[j]) ----------------
// M=NROWS, N=16(batch), K=512. A=W2 (split bf16 hi/lo from registers, coalesced 128B-line
// global reads). B=h fragments from LDS. 3-term split: hi*hi + hi*lo + lo*hi.
__global__ void __launch_bounds__(256, 4) fc2_kernel(const float* __restrict__ W2,
                                                     const float* __restrict__ b2,
                                                     const ushort* __restrict__ h1hi,
                                                     const ushort* __restrict__ h1lo,
                                                     float* __restrict__ h2) {
    __shared__ __align__(16) ushort hB[2][16][520];   // [hi/lo][n=batch][k] bf16, pad row to 520
    for (int u = threadIdx.x; u < 2048; u += 256) {
        int arr = u >> 10, uu = u & 1023;
        int n = uu >> 6, kc = uu & 63;                 // 64 x 16B units per row
        const ushort* src = (arr ? h1lo : h1hi) + n * HIDD + kc * 8;
        *(uint4*)&hB[arr][n][kc * 8] = *(const uint4*)src;
    }
    __syncthreads();

    int tid = threadIdx.x;
    int w = tid >> 6, lane = tid & 63;
    int lm = lane & 15, lq = lane >> 4;
    int j0 = blockIdx.x * 128;                         // 128 rows per block, 2 M-tiles per wave
    int jr0 = j0 + (w * 2) * 16 + lm;     if (jr0 >= NROWS) jr0 = NROWS - 1;
    int jr1 = j0 + (w * 2 + 1) * 16 + lm; if (jr1 >= NROWS) jr1 = NROWS - 1;
    const float* a0p = W2 + (size_t)jr0 * HIDD + lq * 8;   // A-frag: m=lane&15, k=(lane>>4)*8+e
    const float* a1p = W2 + (size_t)jr1 * HIDD + lq * 8;
    const ushort* bhp = &hB[0][lm][lq * 8];                // B-frag: n=lane&15, k=(lane>>4)*8+e
    const ushort* blp = &hB[1][lm][lq * 8];
    f32x4 acc0 = {0.f, 0.f, 0.f, 0.f};
    f32x4 acc1 = {0.f, 0.f, 0.f, 0.f};

#pragma unroll 2
    for (int ks = 0; ks < 16; ++ks) {                  // K-steps of 32
        float4 a0a = *(const float4*)(a0p + ks * 32);
        float4 a0b = *(const float4*)(a0p + ks * 32 + 4);
        float4 a1a = *(const float4*)(a1p + ks * 32);
        float4 a1b = *(const float4*)(a1p + ks * 32 + 4);
        short8 bh = *(const short8*)(bhp + ks * 32);
        short8 bl = *(const short8*)(blp + ks * 32);
        short8 h0, l0, h1v, l1v;
        split8(a0a, a0b, h0, l0);
        split8(a1a, a1b, h1v, l1v);
        acc0 = __builtin_amdgcn_mfma_f32_16x16x32_bf16(h0, bh, acc0, 0, 0, 0);
        acc1 = __builtin_amdgcn_mfma_f32_16x16x32_bf16(h1v, bh, acc1, 0, 0, 0);
        acc0 = __builtin_amdgcn_mfma_f32_16x16x32_bf16(h0, bl, acc0, 0, 0, 0);
        acc1 = __builtin_amdgcn_mfma_f32_16x16x32_bf16(h1v, bl, acc1, 0, 0, 0);
        acc0 = __builtin_amdgcn_mfma_f32_16x16x32_bf16(l0, bh, acc0, 0, 0, 0);
        acc1 = __builtin_amdgcn_mfma_f32_16x16x32_bf16(l1v, bh, acc1, 0, 0, 0);
    }

    // D layout: n(col)=lane&15, m(row)=(lane>>4)*4+reg  [measured m89/m91]
#pragma unroll
    for (int mt = 0; mt < 2; ++mt) {
        f32x4 acc = mt ? acc1 : acc0;
        int jb = j0 + (w * 2 + mt) * 16 + lq * 4;
#pragma unroll
        for (int reg = 0; reg < 4; ++reg) {
            int j = jb + reg;
            if (j < NROWS) {
                float val = fast_tanh(acc[reg] + b2[j]);
                int ii = j & 1;
                int s = j >> 1;
                int c = s / L0LEN;
                int l = s - c * L0LEN;
                h2[((size_t)(ii * 16 + lm) * CFCH + c) * L0LEN + l] = val;
            }
        }
    }
}

// ---------------- fused conv0+conv1: t0 tile in LDS, weights via scalar loads ----------------
// Per logical block (bx, bb, i): 2048 final outputs O in [bx*2048, bx*2048+2048).
// conv0: t0[P] = tanh(b0[co] + sum_ci sum_t w0[ci][co][r+4t] * h2[ci][P/4+4-t]),  r=P&3
//        needed P-window: [p0, p0+519],  p0 = bx*512 - 4  (stored at p' = P-p0-1)
// conv1: out[O] = tanh(b1 + sum_ci sum_t w1[ci][r+4t] * t0[O/4+4-t])
// 1-D grid + XCD pinning: blockIdx%8 -> XCD [m09]; we map batch bb so bb&7 == blockIdx&7,
// so all t1[bb] writes go through one XCD's L2 (matched by final_kernel's read mapping).
#define H2ROW 144
#define T0ROW 520

__global__ void __launch_bounds__(256, 3) convfused_kernel(const float* __restrict__ h2,
        const float* __restrict__ w0G, const float* __restrict__ ctb0,
        const float* __restrict__ w1G, const float* __restrict__ ctb1,
        float* __restrict__ t1) {
    __shared__ float h2S[16 * H2ROW];      // 9.2 KB : h2 window, h2S[ci][xx] = h2[ci][q0+xx]
    __shared__ float t0S[16 * T0ROW];      // 33.3 KB: [co*T0ROW + p'] , p' = p-1 (aligned conv1 reads)

    // XCD-pinned decode: bb&7 == phys&7  (1024 = 8 xcd * (2 bb-hi * 2 i * 32 bx))
    int phys = blockIdx.x;
    int x8 = phys & 7, k = phys >> 3;
    int bb = x8 | ((k & 1) << 3);
    int i  = (k >> 1) & 1;
    int bx = k >> 2;

    int tid = threadIdx.x;
    int r = __builtin_amdgcn_readfirstlane(tid >> 6);  // wave-uniform output phase
    int lane = tid & 63;

    // ---- stage h2 window (140 cols x 16 ci), zero-padded outside [0, L0LEN) ----
    int q0 = (bx << 7) - 4;
    const float* hin = h2 + (size_t)((i * 16 + bb) * 16) * L0LEN;
#pragma unroll 1
    for (int u = tid; u < 16 * 140; u += 256) {
        int ci = u / 140;
        int xx = u - ci * 140;
        int q = q0 + xx;
        h2S[ci * H2ROW + xx] = (q >= 0 && q < L0LEN) ? hin[ci * L0LEN + q] : 0.f;
    }
    __syncthreads();

    int p0 = (bx << 9) - 4;
    const float* w0r = w0G + (((i << 2) + r) << 11);   // [ci][co][t] for this (i, r)

    // ---- conv0 stage: each lane computes quads Qb, Qb+1 (covers Q in [0,128)) for all 16 co ----
    {
        float acc[16][2];
#pragma unroll
        for (int co = 0; co < 16; ++co) { acc[co][0] = 0.f; acc[co][1] = 0.f; }
        int Qb = lane << 1;
#pragma unroll 1
        for (int ci = 0; ci < 16; ++ci) {
            const float* xb = &h2S[ci * H2ROW + Qb];
            float2 xA = *(const float2*)(xb);          // Qb even -> 8B aligned
            float2 xB = *(const float2*)(xb + 2);
            float2 xC = *(const float2*)(xb + 4);
            float2 xD = *(const float2*)(xb + 6);
            float x8v = xb[8];
            float x[9] = {xA.x, xA.y, xB.x, xB.y, xC.x, xC.y, xD.x, xD.y, x8v};
            const float* wci = w0r + (ci << 7);        // wave-uniform -> s_load
#pragma unroll
            for (int co = 0; co < 16; ++co) {
                const float* wrow = wci + (co << 3);
                float4 wa = *(const float4*)wrow;
                float4 wb4 = *(const float4*)(wrow + 4);
                // t ascending, x index = Q + 7 - t  (identical order to unfused conv0)
                acc[co][0] = fmaf(wa.x,  x[7], acc[co][0]);
                acc[co][0] = fmaf(wa.y,  x[6], acc[co][0]);
                acc[co][0] = fmaf(wa.z,  x[5], acc[co][0]);
                acc[co][0] = fmaf(wa.w,  x[4], acc[co][0]);
                acc[co][0] = fmaf(wb4.x, x[3], acc[co][0]);
                acc[co][0] = fmaf(wb4.y, x[2], acc[co][0]);
                acc[co][0] = fmaf(wb4.z, x[1], acc[co][0]);
                acc[co][0] = fmaf(wb4.w, x[0], acc[co][0]);
                acc[co][1] = fmaf(wa.x,  x[8], acc[co][1]);
                acc[co][1] = fmaf(wa.y,  x[7], acc[co][1]);
                acc[co][1] = fmaf(wa.z,  x[6], acc[co][1]);
                acc[co][1] = fmaf(wa.w,  x[5], acc[co][1]);
                acc[co][1] = fmaf(wb4.x, x[4], acc[co][1]);
                acc[co][1] = fmaf(wb4.y, x[3], acc[co][1]);
                acc[co][1] = fmaf(wb4.z, x[2], acc[co][1]);
                acc[co][1] = fmaf(wb4.w, x[1], acc[co][1]);
            }
        }
#pragma unroll
        for (int co = 0; co < 16; ++co) {
            float b0 = ctb0[(i << 4) + co];
#pragma unroll
            for (int j = 0; j < 2; ++j) {
                int p = ((Qb + j) << 2) + r;
                unsigned P = (unsigned)(p0 + p);
                float val = (P < L1LEN) ? fast_tanh(acc[co][j] + b0) : 0.f;  // zero pad like unfused
                if (p >= 1) t0S[co * T0ROW + (p - 1)] = val;
            }
        }
    }

    // ---- conv0 tail: quads 128,129 (one value per thread, 128 threads) ----
    if (tid < 128) {
        int co = tid >> 3;
        int Qt = 128 + ((tid >> 2) & 1);
        int rt = tid & 3;
        float acct = 0.f;
        const float* wt0 = w0G + (((i << 2) + rt) << 11) + (co << 3);
#pragma unroll 1
        for (int ci = 0; ci < 16; ++ci) {
            const float* xb = &h2S[ci * H2ROW + Qt];
            const float* wrow = wt0 + (ci << 7);       // per-lane addr -> vector load (tiny, L2-hot)
#pragma unroll
            for (int t = 0; t < 8; ++t)
                acct = fmaf(wrow[t], xb[7 - t], acct);
        }
        float b0 = ctb0[(i << 4) + co];
        int p = (Qt << 2) + rt;                 // p in [512,519] -> p' in [511,518]
        unsigned P = (unsigned)(p0 + p);
        t0S[co * T0ROW + (p - 1)] = (P < L1LEN) ? fast_tanh(acct + b0) : 0.f;
    }
    __syncthreads();

    // ---- conv1 stage: each lane computes 8 quads (Qb1..Qb1+7), aligned b128 LDS reads ----
    {
        int Qb1 = lane << 3;
        float acc1[8];
#pragma unroll
        for (int j = 0; j < 8; ++j) acc1[j] = 0.f;
        const float* w1r = w1G + (((i << 2) + r) << 7);
#pragma unroll 1
        for (int ci = 0; ci < 16; ++ci) {
            const float* xb = &t0S[ci * T0ROW + Qb1];  // 32B-aligned, lane-stride 16B
            float4 xa = *(const float4*)(xb);
            float4 xv = *(const float4*)(xb + 4);
            float4 xc = *(const float4*)(xb + 8);
            float4 xd = *(const float4*)(xb + 12);
            float x[16] = {xa.x, xa.y, xa.z, xa.w, xv.x, xv.y, xv.z, xv.w,
                           xc.x, xc.y, xc.z, xc.w, xd.x, xd.y, xd.z, xd.w};
            const float* wrow = w1r + (ci << 3);       // wave-uniform -> s_load
            float4 wa = *(const float4*)wrow;
            float4 wb4 = *(const float4*)(wrow + 4);
            float wt[8] = {wa.x, wa.y, wa.z, wa.w, wb4.x, wb4.y, wb4.z, wb4.w};
#pragma unroll
            for (int j = 0; j < 8; ++j) {
#pragma unroll
                for (int t = 0; t < 8; ++t)
                    acc1[j] = fmaf(wt[t], x[j + 7 - t], acc1[j]);
            }
        }
        float bias = ctb1[i];
        float* dst = t1 + (size_t)(i * 16 + bb) * (size_t)N_NODES;
        int o0 = bx << 11;
#pragma unroll
        for (int j = 0; j < 8; ++j) {
            int o = o0 + ((Qb1 + j) << 2) + r;
            dst[o] = fast_tanh(acc1[j] + bias);
        }
    }
}

// ---------------- gather + per-sfc NN + final NN + output linear ----------------
// 1-D grid, XCD-pinned to match convfused: batch b with b&7 == blockIdx&7 reads the
// t1 slices that were written through the same XCD's L2 (1 MB working set / XCD).
__global__ void __launch_bounds__(256) final_kernel(const float* __restrict__ t1,
        const float* __restrict__ sps_w, const float* __restrict__ sps_b,
        const float* __restrict__ final_w, const float* __restrict__ final_b,
        const float* __restrict__ out_w, const float* __restrict__ out_b,
        const int* __restrict__ ord_idx, float* __restrict__ out) {
    int phys = blockIdx.x;
    int x8 = phys & 7, k = phys >> 3;
    int b = x8 | ((k & 1) << 3);
    int chunk = k >> 1;                         // 0..63
    int n0 = ((chunk << 8) | threadIdx.x) << 2; // 4 nodes per thread
    float z[2][4];
#pragma unroll
    for (int i = 0; i < 2; ++i) {
        const int* od = ord_idx + i * N_NODES;
        int4 mid = *(const int4*)(od + n0);
        int idx0 = (n0 == 0) ? mid.x : od[n0 - 1];
        int idx5 = (n0 + 4 >= N_NODES) ? mid.w : od[n0 + 4];
        const float* tb = t1 + ((size_t)(i * 16 + b) << 16);
        float v0 = tb[idx0], v1 = tb[mid.x], v2 = tb[mid.y],
              v3 = tb[mid.z], v4 = tb[mid.w], v5 = tb[idx5];
        const float* sw = sps_w + ((size_t)i * N_NODES + n0) * 3;
        float4 swa = *(const float4*)sw;
        float4 swb = *(const float4*)(sw + 4);
        float4 swc = *(const float4*)(sw + 8);
        float4 sb = *(const float4*)(sps_b + (size_t)i * N_NODES + n0);
        z[i][0] = fast_tanh(fmaf(v0, swa.x, fmaf(v1, swa.y, fmaf(v2, swa.z, sb.x))));
        z[i][1] = fast_tanh(fmaf(v1, swa.w, fmaf(v2, swb.x, fmaf(v3, swb.y, sb.y))));
        z[i][2] = fast_tanh(fmaf(v2, swb.z, fmaf(v3, swb.w, fmaf(v4, swc.x, sb.z))));
        z[i][3] = fast_tanh(fmaf(v3, swc.y, fmaf(v4, swc.z, fmaf(v5, swc.w, sb.w))));
    }
    float4 fwa = *(const float4*)(final_w + (size_t)n0 * 2);
    float4 fwb = *(const float4*)(final_w + (size_t)n0 * 2 + 4);
    float4 fb = *(const float4*)(final_b + n0);
    float4 ow = *(const float4*)(out_w + n0);
    float4 ob = *(const float4*)(out_b + n0);
    float4 r;
    r.x = fmaf(fast_tanh(fmaf(z[0][0], fwa.x, fmaf(z[1][0], fwa.y, fb.x))), ow.x, ob.x);
    r.y = fmaf(fast_tanh(fmaf(z[0][1], fwa.z, fmaf(z[1][1], fwa.w, fb.y))), ow.y, ob.y);
    r.z = fmaf(fast_tanh(fmaf(z[0][2], fwb.x, fmaf(z[1][2], fwb.y, fb.z))), ow.z, ob.z);
    r.w = fmaf(fast_tanh(fmaf(z[0][3], fwb.z, fmaf(z[1][3], fwb.w, fb.w))), ow.w, ob.w);
    *(float4*)(out + ((size_t)b << 16) + n0) = r;
}

extern "C" void kernel_launch(void* const* d_in, const int* in_sizes, int n_in,
                              void* d_out, int out_size, void* d_ws, size_t ws_size,
                              hipStream_t stream) {
    const float* x       = (const float*)d_in[0];
    const float* W1      = (const float*)d_in[1];
    const float* b1      = (const float*)d_in[2];
    const float* W2      = (const float*)d_in[3];
    const float* b2      = (const float*)d_in[4];
    const float* ctw0    = (const float*)d_in[5];
    const float* ctb0    = (const float*)d_in[6];
    const float* ctw1    = (const float*)d_in[7];
    const float* ctb1    = (const float*)d_in[8];
    const float* sps_w   = (const float*)d_in[9];
    const float* sps_b   = (const float*)d_in[10];
    const float* final_w = (const float*)d_in[11];
    const float* final_b = (const float*)d_in[12];
    const float* out_w   = (const float*)d_in[13];
    const float* out_b   = (const float*)d_in[14];
    const int* ord_idx   = (const int*)d_in[15];

    float* ws  = (float*)d_ws;
    float* h2  = ws;                         // 2097664 f  [2][16][16][4097]
    float* t1  = h2 + 2097664;               // 2097152 f  [2][16][65536]
    ushort* h1hi = (ushort*)(t1 + 2097152);  // 8192 ushorts
    ushort* h1lo = h1hi + 8192;
    float* w0G = (float*)(h1lo + 8192);      // 16384 f  [2][4][16][16][8]
    float* w1G = w0G + 16384;                // 1024 f   [2][4][16][8]
    float* out = (float*)d_out;

    hipLaunchKernelGGL(fc1_kernel, dim3(100), dim3(256), 0, stream,
                       x, W1, b1, ctw0, ctw1, h1hi, h1lo, w0G, w1G);
    hipLaunchKernelGGL(fc2_kernel, dim3((NROWS + 127) / 128), dim3(256), 0, stream,
                       W2, b2, h1hi, h1lo, h2);
    hipLaunchKernelGGL(convfused_kernel, dim3(1024), dim3(256), 0, stream,
                       h2, w0G, ctb0, w1G, ctb1, t1);
    hipLaunchKernelGGL(final_kernel, dim3(1024), dim3(256), 0, stream,
                       t1, sps_w, sps_b, final_w, final_b, out_w, out_b,
                       ord_idx, out);
}